// Round 2
// 4237.215 us; speedup vs baseline: 1.8679x; 1.8679x over previous
//
#include <hip/hip_runtime.h>
#include <stdint.h>

// P_TNCN: seq=512, batch=128, states=512, out=256, inv_tau=0.5,
// alpha=0.01, beta=0.5.  float32 I/O.
//
// Per step (per batch row b, independent across b):
//   h_prior = 0.5*h + 0.5*(tanh(h) @ w_r^T + b_r)          [w_i term == 0]
//   x_pred  = tanh(h_prior) @ w_o^T + b_o
//   error   = x_pred - x_t                                   (output)
//   h_post  = h_prior - 0.01*sign(h_prior) - 0.5*(error @ w_f^T)
//
// R4 = R3 resubmit (R3 bench died in container infra, no counters returned;
// nothing in the kernel plausibly kills a container — same sync structure as
// the 7.9ms R2 that ran clean).  Changes vs R2:
//  * Weights packed as f16 pairs (lossless: inputs are bf16-grid and well
//    inside f16 range), activations staged in LDS as f16.
//  * Inner loops use v_dot2_f32_f16 (__builtin_amdgcn_fdot2): 2 MACs/inst,
//    f32 accumulate, no unpack ops.  __has_builtin fallback = cvt+FMA.
//  * Weight loads widened to uint4 (16B = 8 k-values per global load).
//  * BUGFIX vs R2: R2's O2 image only covered kq<64; the kh=1 half of the
//    w_o matvec read w_f data out-of-region.  O4 covers all k=512.
//  * x_t global load hoisted to top of the step loop (latency hidden under
//    Phase A's matvec).
// Workspace: 1 MB.

#define SEQ   512
#define BATCH 128
#define SD    512
#define OD    256

typedef _Float16 h2_t __attribute__((ext_vector_type(2)));

#if __has_builtin(__builtin_amdgcn_fdot2)
#define HAS_FDOT2 1
#else
#define HAS_FDOT2 0
#endif

__device__ __forceinline__ float tanh_fast(float x) {
    float e = __expf(2.0f * x);
    return 1.0f - 2.0f / (e + 1.0f);
}

__device__ __forceinline__ uint32_t pack_h2(float a, float b) {
    h2_t v;
    v.x = (_Float16)a;
    v.y = (_Float16)b;
    return __builtin_bit_cast(uint32_t, v);
}

__device__ __forceinline__ float dot2acc(uint32_t w, uint32_t a, float acc) {
#if HAS_FDOT2
    return __builtin_amdgcn_fdot2(__builtin_bit_cast(h2_t, a),
                                  __builtin_bit_cast(h2_t, w), acc, false);
#else
    h2_t av = __builtin_bit_cast(h2_t, a);
    h2_t wv = __builtin_bit_cast(h2_t, w);
    acc += (float)av.x * (float)wv.x;
    acc += (float)av.y * (float)wv.y;
    return acc;
#endif
}

__device__ __forceinline__ float dot8(uint4 w, uint4 a, float acc) {
    acc = dot2acc(w.x, a.x, acc);
    acc = dot2acc(w.y, a.y, acc);
    acc = dot2acc(w.z, a.z, acc);
    acc = dot2acc(w.w, a.w, acc);
    return acc;
}

// ---------------------------------------------------------------------------
// Pack kernel: transposed, 8-k-packed f16 weight images in workspace.
//   A4 uint4 [64][512] : A4[k8][s] = w_r[s][8k8..8k8+7]     (512 KB)
//   O4 uint4 [64][256] : O4[k8][o] = w_o[o][8k8..8k8+7]     (256 KB)  full k
//   F4 uint4 [32][512] : F4[o8][s] = w_f[s][8o8..8o8+7]     (256 KB)
// total 1 MB of workspace.
// ---------------------------------------------------------------------------
__global__ void pack_weights(const float* __restrict__ w_o,
                             const float* __restrict__ w_r,
                             const float* __restrict__ w_f,
                             uint4* __restrict__ ws)
{
    const int nA = 64 * 512;   // 32768 uint4
    const int nO = 64 * 256;   // 16384
    const int nF = 32 * 512;   // 16384
    int i = blockIdx.x * 256 + threadIdx.x;
    const float* p;
    if (i < nA) {
        int k8 = i >> 9, s = i & 511;
        p = &w_r[s * 512 + 8 * k8];
    } else if (i < nA + nO) {
        int j = i - nA;
        int k8 = j >> 8, o = j & 255;
        p = &w_o[o * 512 + 8 * k8];
    } else if (i < nA + nO + nF) {
        int j = i - nA - nO;
        int o8 = j >> 9, s = j & 511;
        p = &w_f[s * 256 + 8 * o8];
    } else {
        return;
    }
    ws[i] = make_uint4(pack_h2(p[0], p[1]), pack_h2(p[2], p[3]),
                       pack_h2(p[4], p[5]), pack_h2(p[6], p[7]));
}

// ---------------------------------------------------------------------------
// Main sequential scan: one block per batch row, h state in registers (s=tid).
// ---------------------------------------------------------------------------
__global__ __launch_bounds__(512)
void tncn_scan(const float* __restrict__ x,       // [512][128][256]
               const float* __restrict__ h_init,  // [128][512]
               const float* __restrict__ b_o,     // [256]
               const float* __restrict__ b_r,     // [512]
               const uint4* __restrict__ wsv,
               float* __restrict__ out)           // [512][128][256]
{
    const uint4* A4 = wsv;                  // [64][512]
    const uint4* O4 = wsv + 64 * 512;       // [64][256]
    const uint4* F4 = O4 + 64 * 256;        // [32][512]

    __shared__ __align__(16) _Float16 thA[512];  // tanh(h_post) prev step
    __shared__ __align__(16) _Float16 thB[512];  // tanh(h_prior) this step
    __shared__ __align__(16) _Float16 erh[256];  // error vector this step
    __shared__ float part[512];                  // partial sums for x_pred

    const int b   = blockIdx.x;
    const int tid = threadIdx.x;
    const int o   = tid & 255;
    const int kh  = tid >> 8;    // 0/1: k-half for phase B

    const float brf = b_r[tid];
    const float bof = (tid < 256) ? b_o[tid] : 0.0f;

    float hpost = h_init[b * SD + tid];
    thA[tid] = (_Float16)tanh_fast(hpost);
    __syncthreads();

    for (int t = 0; t < SEQ; ++t) {
        // Hoisted x_t load: consumed one matvec later (latency fully hidden).
        float xv = 0.0f;
        if (tid < 256) xv = x[(t * BATCH + b) * OD + o];

        // ---- Phase A: h_prior[s=tid] = 0.5*h + 0.5*(tanh(h)@w_r^T + b_r)
        float acc = 0.0f;
        #pragma unroll 8
        for (int k8 = 0; k8 < 64; ++k8) {
            uint4 u = A4[k8 * 512 + tid];
            uint4 a = *(const uint4*)&thA[8 * k8];
            acc = dot8(u, a, acc);
        }
        float hp = 0.5f * hpost + 0.5f * (acc + brf);
        thB[tid] = (_Float16)tanh_fast(hp);
        __syncthreads();

        // ---- Phase B: x_pred[o] = tanh(h_prior)@w_o^T + b_o ; err = xp - x
        float accB = 0.0f;
        {
            const int k80 = kh * 32;
            #pragma unroll 8
            for (int k8i = 0; k8i < 32; ++k8i) {
                const int k8 = k80 + k8i;
                uint4 u = O4[k8 * 256 + o];
                uint4 a = *(const uint4*)&thB[8 * k8];
                accB = dot8(u, a, accB);
            }
        }
        part[tid] = accB;
        __syncthreads();
        if (tid < 256) {
            float xp = part[tid] + part[tid + 256] + bof;
            float e  = xp - xv;
            erh[tid] = (_Float16)e;
            out[(t * BATCH + b) * OD + tid] = e;
        }
        __syncthreads();

        // ---- Phase C: h_post[s] = h_prior - 0.01*sign(h_prior) - 0.5*(er@w_f^T)
        float accC = 0.0f;
        #pragma unroll 8
        for (int o8 = 0; o8 < 32; ++o8) {
            uint4 u = F4[o8 * 512 + tid];
            uint4 e = *(const uint4*)&erh[8 * o8];
            accC = dot8(u, e, accC);
        }
        float sg = (hp > 0.0f) ? 1.0f : ((hp < 0.0f) ? -1.0f : 0.0f);
        hpost = hp - 0.01f * sg - 0.5f * accC;
        thA[tid] = (_Float16)tanh_fast(hpost);
        __syncthreads();
    }
}

extern "C" void kernel_launch(void* const* d_in, const int* in_sizes, int n_in,
                              void* d_out, int out_size, void* d_ws, size_t ws_size,
                              hipStream_t stream)
{
    // setup_inputs order: x, h_init, w_o, b_o, w_r, b_r, w_f, w_i
    const float* x  = (const float*)d_in[0];
    const float* h0 = (const float*)d_in[1];
    const float* wo = (const float*)d_in[2];
    const float* bo = (const float*)d_in[3];
    const float* wr = (const float*)d_in[4];
    const float* br = (const float*)d_in[5];
    const float* wf = (const float*)d_in[6];
    // d_in[7] (w_i) multiplies a zeros tensor in the reference — unused.

    uint4* ws = (uint4*)d_ws;
    float* out = (float*)d_out;

    const int total_pack = 64 * 512 + 64 * 256 + 32 * 512;  // 65536 uint4
    pack_weights<<<(total_pack + 255) / 256, 256, 0, stream>>>(wo, wr, wf, ws);
    tncn_scan<<<BATCH, 512, 0, stream>>>(x, h0, bo, br, ws, out);
}